// Round 2
// baseline (1011.871 us; speedup 1.0000x reference)
//
#include <hip/hip_runtime.h>

typedef _Float16 f16;
typedef f16 f16x8 __attribute__((ext_vector_type(8)));
typedef f16 f16x4 __attribute__((ext_vector_type(4)));
typedef f16 f16x2 __attribute__((ext_vector_type(2)));
typedef float f32x4 __attribute__((ext_vector_type(4)));

#define MFMA16(a, b, c) __builtin_amdgcn_mfma_f32_16x16x32_f16(a, b, c, 0, 0, 0)

// XOR-swizzled LDS addressing: 8-element groups, conflict-free-ish fragment reads
__device__ __forceinline__ int swz(int row, int col, int width) {
    return row * width + ((((col >> 3) ^ (row & 7)) << 3) | (col & 7));
}

#define TWO_PI 6.283185307179586f
__device__ __forceinline__ float angf(int p) { return TWO_PI * (float)(p & 255) * (1.0f / 256.0f); }

// ---------------------------------------------------------------------------
// PREP: block 0 -> FiLM; blocks 1..16 -> DFT tables
// ---------------------------------------------------------------------------
__global__ __launch_bounds__(256) void prep_kernel(
    const float* __restrict__ t_emb, const float* __restrict__ film_w1,
    const float* __restrict__ film_b1, const float* __restrict__ film_w2,
    const float* __restrict__ film_b2, const float* __restrict__ bypass_b,
    float* __restrict__ scale, float* __restrict__ bias2,
    f16* __restrict__ FmatT, f16* __restrict__ Tab2T,
    f16* __restrict__ CSTtT, f16* __restrict__ IWT)
{
    __shared__ float hbuf[16 * 64];
    int blk = blockIdx.x, t = threadIdx.x;
    if (blk == 0) {
        // FiLM: h = silu(t_emb@W1 + b1); gb = h@W2 + b2 -> scale=1+gamma, bias2=beta+bypass_b
        for (int r = 0; r < 4; ++r) {
            int idx = t + r * 256;
            int bb = idx >> 6, j = idx & 63;
            float acc = film_b1[j];
            for (int i = 0; i < 64; ++i) acc += t_emb[bb * 64 + i] * film_w1[i * 64 + j];
            hbuf[idx] = acc / (1.0f + __expf(-acc));
        }
        __syncthreads();
        for (int r = 0; r < 8; ++r) {
            int idx = t + r * 256;
            int bb = idx >> 7, j = idx & 127;
            float acc = film_b2[j];
            for (int i = 0; i < 64; ++i) acc += hbuf[bb * 64 + i] * film_w2[i * 128 + j];
            if (j < 64) scale[bb * 64 + j] = 1.0f + acc;
            else        bias2[bb * 64 + (j - 64)] = acc + bypass_b[j - 64];
        }
    } else {
        int bid = blk - 1;
        for (int r = 0; r < 20; ++r) {
            int e = bid * 5120 + r * 256 + t;
            float val;
            if (e < 16384) {
                int c = e >> 8, w = e & 255;
                if (c < 32) val = __cosf(angf(c * w)) * (1.0f / 256.0f);
                else        val = -__sinf(angf((c - 32) * w)) * (1.0f / 256.0f);
                FmatT[e] = (f16)val;
            } else if (e < 49152) {
                int e2 = e - 16384;
                int n = e2 >> 9, k = e2 & 511;
                int h = k & 255;
                bool first = (k < 256);
                if (n < 32) val = first ? __cosf(angf(n * h)) : __sinf(angf(n * h));
                else {
                    int m = n - 32;
                    val = first ? -__sinf(angf(m * h)) : __cosf(angf(m * h));
                }
                Tab2T[e2] = (f16)val;
            } else if (e < 65536) {
                int e2 = e - 49152;
                int h = e2 >> 6, k = e2 & 63;
                val = (k < 32) ? __cosf(angf(k * h)) : __sinf(angf((k - 32) * h));
                CSTtT[e2] = (f16)val;
            } else {
                int e2 = e - 65536;
                int w = e2 >> 6, c = e2 & 63;
                if (c == 0)      val = 1.0f / 256.0f;
                else if (c < 32) val = (2.0f / 256.0f) * __cosf(angf(c * w));
                else             val = -(2.0f / 256.0f) * __sinf(angf((c - 32) * w));
                IWT[e2] = (f16)val;
            }
        }
    }
}

// ---------------------------------------------------------------------------
// K1: blocks 0..255: w transpose; blocks 256..4351: row DFT.
// ---------------------------------------------------------------------------
__global__ __launch_bounds__(256) void k1_rowfft(
    const float* __restrict__ x, const f16* __restrict__ FmatT, f16* __restrict__ T1,
    const float* __restrict__ w_real, const float* __restrict__ w_imag,
    f16* __restrict__ wT)
{
    __shared__ f16 A[64 * 256];
    __shared__ f16 Tr[64 * 72];
    int blk = blockIdx.x, t = threadIdx.x;
    if (blk < 256) {
        int k = blk >> 3, og = blk & 7;
        int i = t & 63, oq = t >> 6;
#pragma unroll
        for (int os = 0; os < 2; ++os) {
            int o = og * 8 + oq * 2 + os;
            const float* wr = w_real + ((long)(i * 64 + o) * 1024 + k * 32);
            const float* wi = w_imag + ((long)(i * 64 + o) * 1024 + k * 32);
#pragma unroll
            for (int l4 = 0; l4 < 8; ++l4) {
                float4 r = *(const float4*)(wr + l4 * 4);
                float4 m = *(const float4*)(wi + l4 * 4);
                float rv[4] = {r.x, r.y, r.z, r.w};
                float mv[4] = {m.x, m.y, m.z, m.w};
#pragma unroll
                for (int u = 0; u < 4; ++u) {
                    int l = l4 * 4 + u;
                    f16x2 p; p[0] = (f16)rv[u]; p[1] = (f16)mv[u];
                    *(f16x2*)(wT + (((long)((l * 32 + k) * 64 + o)) * 64 + i) * 2) = p;
                }
            }
        }
        return;
    }
    int kb = blk - 256;
    int b = kb >> 8, ci = (kb >> 2) & 63, hc = kb & 3;
    const float* xt = x + (((long)(b * 64 + ci) * 256 + hc * 64) * 256);
    for (int j = 0; j < 16; ++j) {
        int f = j * 256 + t;            // float4 index
        float4 v = *(const float4*)(xt + f * 4);
        int m = f >> 6, col = (f * 4) & 255;
        f16x4 h4; h4[0] = (f16)v.x; h4[1] = (f16)v.y; h4[2] = (f16)v.z; h4[3] = (f16)v.w;
        *(f16x4*)(A + swz(m, col, 256)) = h4;
    }
    __syncthreads();
    int lane = t & 63, wv = t >> 6, kq = lane >> 4, ln = lane & 15;
    int mrow = wv * 16 + ln;
    f32x4 acc[4] = {};
    for (int ks = 0; ks < 8; ++ks) {
        int k0 = ks * 32 + kq * 8;
        f16x8 af = *(const f16x8*)(A + swz(mrow, k0, 256));
#pragma unroll
        for (int nt = 0; nt < 4; ++nt) {
            f16x8 bf = *(const f16x8*)(FmatT + (nt * 16 + ln) * 256 + k0);
            acc[nt] = MFMA16(af, bf, acc[nt]);
        }
    }
#pragma unroll
    for (int nt = 0; nt < 4; ++nt)
#pragma unroll
        for (int r = 0; r < 4; ++r) {
            int n_e = nt * 16 + ln;
            int m_e = wv * 16 + kq * 4 + r;
            Tr[n_e * 72 + m_e] = (f16)acc[nt][r];
        }
    __syncthreads();
    int c = t >> 2, q = t & 3;
    f16x8 v0 = *(const f16x8*)(Tr + c * 72 + q * 16);
    f16x8 v1 = *(const f16x8*)(Tr + c * 72 + q * 16 + 8);
    f16* dst = T1 + ((long)(b * 64 + c) * 64 + ci) * 256 + hc * 64 + q * 16;
    *(f16x8*)(dst) = v0;
    *(f16x8*)(dst + 8) = v1;
}

// ---------------------------------------------------------------------------
// K2: per (b,l): col DFT (MFMA) -> channel mix (VALU) -> inverse col DFT (MFMA)
// ---------------------------------------------------------------------------
__global__ __launch_bounds__(256) void k2_spec(
    const f16* __restrict__ T1, const f16* __restrict__ Tab2T,
    const f16* __restrict__ wT, const f16* __restrict__ CSTtT,
    f16* __restrict__ Gmat)
{
    __shared__ union SMU {
        f16 U[64 * 512];                              // 64 KB
        struct { f16 Astk[128 * 64]; f16 Cbuf[64 * 136]; } p2;
    } sm;
    __shared__ float Xf2[64 * 64];                    // [i][2k+(0:Re,1:Im)]
    int blk = blockIdx.x, t = threadIdx.x;
    int xcd = blk & 7, i2 = blk >> 3;
    int l = xcd * 4 + (i2 & 3), b = i2 >> 2;
    const f16* pre = T1 + (long)(b * 64 + l) * 16384;
    const f16* pim = T1 + (long)(b * 64 + 32 + l) * 16384;
    for (int j = 0; j < 16; ++j) {
        int s = j * 256 + t;
        int ii = s >> 6, h = (s & 63) * 4;
        f16x4 vre = *(const f16x4*)(pre + s * 4);
        *(f16x4*)(sm.U + swz(ii, h, 512)) = vre;
        f16x4 vim = *(const f16x4*)(pim + s * 4);
        *(f16x4*)(sm.U + swz(ii, 256 + h, 512)) = vim;
    }
    __syncthreads();
    int lane = t & 63, wv = t >> 6, kq = lane >> 4, ln = lane & 15;
    {   // stage a: Xf = U @ Tab2
        f32x4 acc[4] = {};
        int row = wv * 16 + ln;
        for (int ks = 0; ks < 16; ++ks) {
            int k0 = ks * 32 + kq * 8;
            f16x8 af = *(const f16x8*)(sm.U + swz(row, k0, 512));
#pragma unroll
            for (int nt = 0; nt < 4; ++nt) {
                f16x8 bf = *(const f16x8*)(Tab2T + (nt * 16 + ln) * 512 + k0);
                acc[nt] = MFMA16(af, bf, acc[nt]);
            }
        }
#pragma unroll
        for (int nt = 0; nt < 4; ++nt)
#pragma unroll
            for (int r = 0; r < 4; ++r) {
                int n_e = nt * 16 + ln;
                int i_e = wv * 16 + kq * 4 + r;
                Xf2[i_e * 64 + (n_e & 31) * 2 + (n_e >> 5)] = acc[nt][r];
            }
    }
    __syncthreads();
    {   // mix
        int o = t & 63, kg = t >> 6;
        for (int j = 0; j < 8; ++j) {
            int k = kg * 8 + j;
            const f16* wp = wT + ((long)((l * 32 + k) * 64 + o)) * 64 * 2;
            const float2* xp2 = (const float2*)(Xf2 + k * 2);
            float fre = 0.0f, fim = 0.0f;
#pragma unroll 4
            for (int i4 = 0; i4 < 16; ++i4) {
                f16x8 w4 = *(const f16x8*)(wp + i4 * 8);
#pragma unroll
                for (int u = 0; u < 4; ++u) {
                    float2 xv = xp2[(i4 * 4 + u) * 32];
                    float wr = (float)w4[u * 2], wi = (float)w4[u * 2 + 1];
                    fre += xv.x * wr - xv.y * wi;
                    fim += xv.x * wi + xv.y * wr;
                }
            }
            sm.p2.Astk[swz(o,       k,      64)] = (f16)fre;
            sm.p2.Astk[swz(o,       32 + k, 64)] = (f16)(-fim);
            sm.p2.Astk[swz(64 + o,  k,      64)] = (f16)fim;
            sm.p2.Astk[swz(64 + o,  32 + k, 64)] = (f16)fre;
        }
    }
    __syncthreads();
    for (int ch = 0; ch < 4; ++ch) {
        f32x4 acc[2][4] = {};
        int rbase = wv * 32;
        for (int ks = 0; ks < 2; ++ks) {
            int k0 = ks * 32 + kq * 8;
            f16x8 bf[4];
#pragma unroll
            for (int nt = 0; nt < 4; ++nt)
                bf[nt] = *(const f16x8*)(CSTtT + (ch * 64 + nt * 16 + ln) * 64 + k0);
#pragma unroll
            for (int mi = 0; mi < 2; ++mi) {
                f16x8 af = *(const f16x8*)(sm.p2.Astk + swz(rbase + mi * 16 + ln, k0, 64));
#pragma unroll
                for (int nt = 0; nt < 4; ++nt)
                    acc[mi][nt] = MFMA16(af, bf[nt], acc[mi][nt]);
            }
        }
        __syncthreads();
#pragma unroll
        for (int mi = 0; mi < 2; ++mi)
#pragma unroll
            for (int nt = 0; nt < 4; ++nt)
#pragma unroll
                for (int r = 0; r < 4; ++r) {
                    int m_e = rbase + mi * 16 + kq * 4 + r;
                    int n_e = nt * 16 + ln;
                    sm.p2.Cbuf[n_e * 136 + m_e] = (f16)acc[mi][nt][r];
                }
        __syncthreads();
        int h_l = t >> 2, seg = t & 3;
        int h_g = ch * 64 + h_l;
        const f16* src = sm.p2.Cbuf + h_l * 136 + seg * 32;
        f16x8 a0 = *(const f16x8*)(src);
        f16x8 a1 = *(const f16x8*)(src + 8);
        f16x8 a2 = *(const f16x8*)(src + 16);
        f16x8 a3 = *(const f16x8*)(src + 24);
        f16* gd = Gmat + ((long)(b * 256 + h_g)) * 4096 + l * 64 + (seg >= 2 ? 2048 : 0) + (seg & 1) * 32;
        *(f16x8*)(gd) = a0;
        *(f16x8*)(gd + 8) = a1;
        *(f16x8*)(gd + 16) = a2;
        *(f16x8*)(gd + 24) = a3;
    }
}

// ---------------------------------------------------------------------------
// K3 DIAGNOSTIC: body repeated REP3 times (idempotent — same stores each rep).
// Inflates k3's dispatch duration past the 163 µs poison fills so it lands in
// rocprof top-5 WITH counters (hbm_gbps / MfmaUtil / VALUBusy / Occupancy /
// LDS conflicts). True k3 dur = shown dur / 5.
// ---------------------------------------------------------------------------
#define REP3 5
__global__ __launch_bounds__(256) void k3_out(
    const float* __restrict__ x, const f16* __restrict__ Gmat,
    const f16* __restrict__ IWT, const float* __restrict__ bypass_w,
    const float* __restrict__ scale, const float* __restrict__ bias2,
    float* __restrict__ out)
{
    __shared__ f16 BT[128 * 128];
    __shared__ f16 Amat[64 * 128];
    __shared__ float biasSh[64];
    int blk = blockIdx.x, t = threadIdx.x;
    int g = blk >> 4, rr = blk & 15;
    int half = rr >> 3;
    int pair = g * 8 + (rr & 7);
    int b = pair >> 8, h = pair & 255;
    for (int rep = 0; rep < REP3; ++rep) {
    {   // x transpose -> BT[w][i]
        int ipair = t >> 3, q = t & 7;
        const float* xlo = x + ((long)(b * 64 + 2 * ipair) * 256 + h) * 256 + half * 128;
        const float* xhi = xlo + 65536;
        for (int j = 0; j < 4; ++j) {
            int w4 = (q + j * 8) * 4;
            float4 lo = *(const float4*)(xlo + w4);
            float4 hi = *(const float4*)(xhi + w4);
            float lov[4] = {lo.x, lo.y, lo.z, lo.w};
            float hiv[4] = {hi.x, hi.y, hi.z, hi.w};
#pragma unroll
            for (int u = 0; u < 4; ++u) {
                f16x2 pr; pr[0] = (f16)lov[u]; pr[1] = (f16)hiv[u];
                *(f16x2*)(BT + swz(w4 + u, 2 * ipair, 128)) = pr;
            }
        }
    }
    {   // IWT -> BT[w][64+c]
        int w_l = t >> 1, cs = t & 1;
        const f16* src = IWT + (half * 128 + w_l) * 64 + cs * 32;
        for (int u = 0; u < 8; ++u) {
            f16x4 v = *(const f16x4*)(src + u * 4);
            *(f16x4*)(BT + swz(w_l, 64 + cs * 32 + u * 4, 128)) = v;
        }
    }
    {   // bypass_w -> Amat[o][i]
        int o = t >> 2, s4 = t & 3;
        const float* bwp = bypass_w + o * 64 + s4 * 16;
        for (int u = 0; u < 4; ++u) {
            float4 v = *(const float4*)(bwp + u * 4);
            f16x4 hv; hv[0] = (f16)v.x; hv[1] = (f16)v.y; hv[2] = (f16)v.z; hv[3] = (f16)v.w;
            *(f16x4*)(Amat + swz(o, s4 * 16 + u * 4, 128)) = hv;
        }
    }
    {   // (1+gamma)*G -> Amat[o][64+c]
        int c = t >> 2, s4 = t & 3;
        const f16* gp = Gmat + ((long)(b * 256 + h) * 64 + c) * 64 + s4 * 16;
        f16x8 g0 = *(const f16x8*)(gp);
        f16x8 g1 = *(const f16x8*)(gp + 8);
        float sc[16];
        for (int qq = 0; qq < 4; ++qq) {
            float4 s = *(const float4*)(scale + b * 64 + s4 * 16 + qq * 4);
            sc[qq * 4 + 0] = s.x; sc[qq * 4 + 1] = s.y; sc[qq * 4 + 2] = s.z; sc[qq * 4 + 3] = s.w;
        }
#pragma unroll
        for (int u = 0; u < 8; ++u) {
            Amat[swz(s4 * 16 + u, 64 + c, 128)] = (f16)((float)g0[u] * sc[u]);
            Amat[swz(s4 * 16 + 8 + u, 64 + c, 128)] = (f16)((float)g1[u] * sc[8 + u]);
        }
    }
    if (t < 64) biasSh[t] = bias2[b * 64 + t];
    __syncthreads();

    int lane = t & 63, wv = t >> 6, kq = lane >> 4, ln = lane & 15;
    f32x4 acc[4][2] = {};
    for (int ks = 0; ks < 4; ++ks) {
        int k0 = ks * 32 + kq * 8;
        f16x8 bf[2];
#pragma unroll
        for (int nt = 0; nt < 2; ++nt)
            bf[nt] = *(const f16x8*)(BT + swz(wv * 32 + nt * 16 + ln, k0, 128));
#pragma unroll
        for (int mt = 0; mt < 4; ++mt) {
            f16x8 af = *(const f16x8*)(Amat + swz(mt * 16 + ln, k0, 128));
#pragma unroll
            for (int nt = 0; nt < 2; ++nt)
                acc[mt][nt] = MFMA16(af, bf[nt], acc[mt][nt]);
        }
    }
    long obase = ((long)(b * 64) * 256 + h) * 256 + half * 128;
#pragma unroll
    for (int mt = 0; mt < 4; ++mt)
#pragma unroll
        for (int nt = 0; nt < 2; ++nt)
#pragma unroll
            for (int r = 0; r < 4; ++r) {
                int o = mt * 16 + kq * 4 + r;
                int n = wv * 32 + nt * 16 + ln;
                float v = acc[mt][nt][r] + biasSh[o];
                float uu = 0.7978845608028654f * (v + 0.044715f * v * v * v);
                float e = __expf(2.0f * uu);
                float th = 1.0f - 2.0f / (e + 1.0f);
                __builtin_nontemporal_store(0.5f * v * (1.0f + th),
                                            &out[obase + (long)o * 65536 + n]);
            }
    __syncthreads();   // all lanes done with BT/Amat before next rep overwrites
    }
}

// ---------------------------------------------------------------------------
extern "C" void kernel_launch(void* const* d_in, const int* in_sizes, int n_in,
                              void* d_out, int out_size, void* d_ws, size_t ws_size,
                              hipStream_t stream) {
    const float* x        = (const float*)d_in[0];
    const float* t_emb    = (const float*)d_in[1];
    const float* w_real   = (const float*)d_in[2];
    const float* w_imag   = (const float*)d_in[3];
    const float* film_w1  = (const float*)d_in[4];
    const float* film_b1  = (const float*)d_in[5];
    const float* film_w2  = (const float*)d_in[6];
    const float* film_b2  = (const float*)d_in[7];
    const float* bypass_w = (const float*)d_in[8];
    const float* bypass_b = (const float*)d_in[9];
    float* out = (float*)d_out;
    char* ws = (char*)d_ws;

    float* scale = (float*)(ws + 0);          // 4 KB
    float* bias2 = (float*)(ws + 4096);       // 4 KB
    f16* FmatT = (f16*)(ws + 8192);           // 32 KB
    f16* Tab2T = (f16*)(ws + 40960);          // 64 KB
    f16* CSTtT = (f16*)(ws + 106496);         // 32 KB
    f16* IWT   = (f16*)(ws + 139264);         // 32 KB
    f16* wT    = (f16*)(ws + 172032);         // 16 MB
    f16* T1    = (f16*)(ws + 16949248);       // 32 MB
    f16* Gmat  = (f16*)(ws + 50503680);       // 32 MB  (total 84,058,112 B)

    hipLaunchKernelGGL(prep_kernel, dim3(17), dim3(256), 0, stream,
                       t_emb, film_w1, film_b1, film_w2, film_b2, bypass_b,
                       scale, bias2, FmatT, Tab2T, CSTtT, IWT);
    hipLaunchKernelGGL(k1_rowfft, dim3(4352), dim3(256), 0, stream, x, FmatT, T1,
                       w_real, w_imag, wT);
    hipLaunchKernelGGL(k2_spec, dim3(512), dim3(256), 0, stream, T1, Tab2T, wT, CSTtT, Gmat);
    hipLaunchKernelGGL(k3_out, dim3(8192), dim3(256), 0, stream, x, Gmat, IWT,
                       bypass_w, scale, bias2, out);
}

// Round 5
// 657.285 us; speedup vs baseline: 1.5395x; 1.5395x over previous
//
#include <hip/hip_runtime.h>

typedef _Float16 f16;
typedef f16 f16x8 __attribute__((ext_vector_type(8)));
typedef f16 f16x4 __attribute__((ext_vector_type(4)));
typedef f16 f16x2 __attribute__((ext_vector_type(2)));
typedef float f32x4 __attribute__((ext_vector_type(4)));

#define MFMA16(a, b, c) __builtin_amdgcn_mfma_f32_16x16x32_f16(a, b, c, 0, 0, 0)

// XOR-swizzled LDS addressing: 8-element groups
__device__ __forceinline__ int swz(int row, int col, int width) {
    return row * width + ((((col >> 3) ^ (row & 7)) << 3) | (col & 7));
}
// triple-XOR variant: also folds (row>>3) so accesses whose rows are
// multiples of 4 (k3's x-transpose writes) still spread across all banks.
// Bank check (x-transpose write, 64 lanes): g takes 8 values -> 32 banks
// (~2-way, free per m136) vs swz's 4 values -> 16 banks (4-way, 1.58x).
__device__ __forceinline__ int swz3(int row, int col, int width) {
    return row * width + ((((col >> 3) ^ (row & 7) ^ ((row >> 3) & 7)) << 3) | (col & 7));
}

#define TWO_PI 6.283185307179586f
__device__ __forceinline__ float angf(int p) { return TWO_PI * (float)(p & 255) * (1.0f / 256.0f); }

// ---------------------------------------------------------------------------
// PREP: block 0 -> FiLM; blocks 1..16 -> DFT tables
// ---------------------------------------------------------------------------
__global__ __launch_bounds__(256) void prep_kernel(
    const float* __restrict__ t_emb, const float* __restrict__ film_w1,
    const float* __restrict__ film_b1, const float* __restrict__ film_w2,
    const float* __restrict__ film_b2, const float* __restrict__ bypass_b,
    float* __restrict__ scale, float* __restrict__ bias2,
    f16* __restrict__ FmatT, f16* __restrict__ Tab2T,
    f16* __restrict__ CSTtT, f16* __restrict__ IWT)
{
    __shared__ float hbuf[16 * 64];
    int blk = blockIdx.x, t = threadIdx.x;
    if (blk == 0) {
        for (int r = 0; r < 4; ++r) {
            int idx = t + r * 256;
            int bb = idx >> 6, j = idx & 63;
            float acc = film_b1[j];
            for (int i = 0; i < 64; ++i) acc += t_emb[bb * 64 + i] * film_w1[i * 64 + j];
            hbuf[idx] = acc / (1.0f + __expf(-acc));
        }
        __syncthreads();
        for (int r = 0; r < 8; ++r) {
            int idx = t + r * 256;
            int bb = idx >> 7, j = idx & 127;
            float acc = film_b2[j];
            for (int i = 0; i < 64; ++i) acc += hbuf[bb * 64 + i] * film_w2[i * 128 + j];
            if (j < 64) scale[bb * 64 + j] = 1.0f + acc;
            else        bias2[bb * 64 + (j - 64)] = acc + bypass_b[j - 64];
        }
    } else {
        int bid = blk - 1;
        for (int r = 0; r < 20; ++r) {
            int e = bid * 5120 + r * 256 + t;
            float val;
            if (e < 16384) {
                int c = e >> 8, w = e & 255;
                if (c < 32) val = __cosf(angf(c * w)) * (1.0f / 256.0f);
                else        val = -__sinf(angf((c - 32) * w)) * (1.0f / 256.0f);
                FmatT[e] = (f16)val;
            } else if (e < 49152) {
                int e2 = e - 16384;
                int n = e2 >> 9, k = e2 & 511;
                int h = k & 255;
                bool first = (k < 256);
                if (n < 32) val = first ? __cosf(angf(n * h)) : __sinf(angf(n * h));
                else {
                    int m = n - 32;
                    val = first ? -__sinf(angf(m * h)) : __cosf(angf(m * h));
                }
                Tab2T[e2] = (f16)val;
            } else if (e < 65536) {
                int e2 = e - 49152;
                int h = e2 >> 6, k = e2 & 63;
                val = (k < 32) ? __cosf(angf(k * h)) : __sinf(angf((k - 32) * h));
                CSTtT[e2] = (f16)val;
            } else {
                int e2 = e - 65536;
                int w = e2 >> 6, c = e2 & 63;
                if (c == 0)      val = 1.0f / 256.0f;
                else if (c < 32) val = (2.0f / 256.0f) * __cosf(angf(c * w));
                else             val = -(2.0f / 256.0f) * __sinf(angf((c - 32) * w));
                IWT[e2] = (f16)val;
            }
        }
    }
}

// ---------------------------------------------------------------------------
// K1: blocks 0..255: w transpose (overlaps row-DFT ramp; wT consumed by K2);
//     blocks 256..4351: row DFT.
// row DFT: block=(b,i,hc): C[64h x 64c] = x[64h x 256w] @ Fmat[256 x 64]
// writes T1 planes [b][c][i][h] (f16)
// ---------------------------------------------------------------------------
__global__ __launch_bounds__(256) void k1_rowfft(
    const float* __restrict__ x, const f16* __restrict__ FmatT, f16* __restrict__ T1,
    const float* __restrict__ w_real, const float* __restrict__ w_imag,
    f16* __restrict__ wT)
{
    __shared__ f16 A[64 * 256];
    __shared__ f16 Tr[64 * 72];
    int blk = blockIdx.x, t = threadIdx.x;
    if (blk < 256) {
        int k = blk >> 3, og = blk & 7;
        int i = t & 63, oq = t >> 6;
#pragma unroll
        for (int os = 0; os < 2; ++os) {
            int o = og * 8 + oq * 2 + os;
            const float* wr = w_real + ((long)(i * 64 + o) * 1024 + k * 32);
            const float* wi = w_imag + ((long)(i * 64 + o) * 1024 + k * 32);
#pragma unroll
            for (int l4 = 0; l4 < 8; ++l4) {
                float4 r = *(const float4*)(wr + l4 * 4);
                float4 m = *(const float4*)(wi + l4 * 4);
                float rv[4] = {r.x, r.y, r.z, r.w};
                float mv[4] = {m.x, m.y, m.z, m.w};
#pragma unroll
                for (int u = 0; u < 4; ++u) {
                    int l = l4 * 4 + u;
                    f16x2 p; p[0] = (f16)rv[u]; p[1] = (f16)mv[u];
                    *(f16x2*)(wT + (((long)((l * 32 + k) * 64 + o)) * 64 + i) * 2) = p;
                }
            }
        }
        return;
    }
    int kb = blk - 256;
    int b = kb >> 8, ci = (kb >> 2) & 63, hc = kb & 3;
    const float* xt = x + (((long)(b * 64 + ci) * 256 + hc * 64) * 256);
    for (int j = 0; j < 16; ++j) {
        int f = j * 256 + t;            // float4 index
        float4 v = *(const float4*)(xt + f * 4);
        int m = f >> 6, col = (f * 4) & 255;
        f16x4 h4; h4[0] = (f16)v.x; h4[1] = (f16)v.y; h4[2] = (f16)v.z; h4[3] = (f16)v.w;
        *(f16x4*)(A + swz(m, col, 256)) = h4;
    }
    __syncthreads();
    int lane = t & 63, wv = t >> 6, kq = lane >> 4, ln = lane & 15;
    int mrow = wv * 16 + ln;
    f32x4 acc[4] = {};
    for (int ks = 0; ks < 8; ++ks) {
        int k0 = ks * 32 + kq * 8;
        f16x8 af = *(const f16x8*)(A + swz(mrow, k0, 256));
#pragma unroll
        for (int nt = 0; nt < 4; ++nt) {
            f16x8 bf = *(const f16x8*)(FmatT + (nt * 16 + ln) * 256 + k0);
            acc[nt] = MFMA16(af, bf, acc[nt]);
        }
    }
#pragma unroll
    for (int nt = 0; nt < 4; ++nt)
#pragma unroll
        for (int r = 0; r < 4; ++r) {
            int n_e = nt * 16 + ln;
            int m_e = wv * 16 + kq * 4 + r;
            Tr[n_e * 72 + m_e] = (f16)acc[nt][r];
        }
    __syncthreads();
    int c = t >> 2, q = t & 3;
    f16x8 v0 = *(const f16x8*)(Tr + c * 72 + q * 16);
    f16x8 v1 = *(const f16x8*)(Tr + c * 72 + q * 16 + 8);
    f16* dst = T1 + ((long)(b * 64 + c) * 64 + ci) * 256 + hc * 64 + q * 16;
    *(f16x8*)(dst) = v0;
    *(f16x8*)(dst + 8) = v1;
}

// ---------------------------------------------------------------------------
// K2: per (b,l): col DFT (MFMA) -> channel mix (VALU) -> inverse col DFT (MFMA)
// XCD-aware decode: each XCD owns 4 contiguous l-slices (wT working set 2 MB).
// ---------------------------------------------------------------------------
__global__ __launch_bounds__(256) void k2_spec(
    const f16* __restrict__ T1, const f16* __restrict__ Tab2T,
    const f16* __restrict__ wT, const f16* __restrict__ CSTtT,
    f16* __restrict__ Gmat)
{
    __shared__ union SMU {
        f16 U[64 * 512];                              // 64 KB
        struct { f16 Astk[128 * 64]; f16 Cbuf[64 * 136]; } p2;
    } sm;
    __shared__ float Xf2[64 * 64];                    // [i][2k+(0:Re,1:Im)]
    int blk = blockIdx.x, t = threadIdx.x;
    int xcd = blk & 7, i2 = blk >> 3;
    int l = xcd * 4 + (i2 & 3), b = i2 >> 2;
    const f16* pre = T1 + (long)(b * 64 + l) * 16384;
    const f16* pim = T1 + (long)(b * 64 + 32 + l) * 16384;
    for (int j = 0; j < 16; ++j) {
        int s = j * 256 + t;
        int ii = s >> 6, h = (s & 63) * 4;
        f16x4 vre = *(const f16x4*)(pre + s * 4);
        *(f16x4*)(sm.U + swz(ii, h, 512)) = vre;
        f16x4 vim = *(const f16x4*)(pim + s * 4);
        *(f16x4*)(sm.U + swz(ii, 256 + h, 512)) = vim;
    }
    __syncthreads();
    int lane = t & 63, wv = t >> 6, kq = lane >> 4, ln = lane & 15;
    {   // stage a: Xf = U @ Tab2
        f32x4 acc[4] = {};
        int row = wv * 16 + ln;
        for (int ks = 0; ks < 16; ++ks) {
            int k0 = ks * 32 + kq * 8;
            f16x8 af = *(const f16x8*)(sm.U + swz(row, k0, 512));
#pragma unroll
            for (int nt = 0; nt < 4; ++nt) {
                f16x8 bf = *(const f16x8*)(Tab2T + (nt * 16 + ln) * 512 + k0);
                acc[nt] = MFMA16(af, bf, acc[nt]);
            }
        }
#pragma unroll
        for (int nt = 0; nt < 4; ++nt)
#pragma unroll
            for (int r = 0; r < 4; ++r) {
                int n_e = nt * 16 + ln;
                int i_e = wv * 16 + kq * 4 + r;
                Xf2[i_e * 64 + (n_e & 31) * 2 + (n_e >> 5)] = acc[nt][r];
            }
    }
    __syncthreads();
    {   // mix
        int o = t & 63, kg = t >> 6;
        for (int j = 0; j < 8; ++j) {
            int k = kg * 8 + j;
            const f16* wp = wT + ((long)((l * 32 + k) * 64 + o)) * 64 * 2;
            const float2* xp2 = (const float2*)(Xf2 + k * 2);
            float fre = 0.0f, fim = 0.0f;
#pragma unroll 4
            for (int i4 = 0; i4 < 16; ++i4) {
                f16x8 w4 = *(const f16x8*)(wp + i4 * 8);
#pragma unroll
                for (int u = 0; u < 4; ++u) {
                    float2 xv = xp2[(i4 * 4 + u) * 32];
                    float wr = (float)w4[u * 2], wi = (float)w4[u * 2 + 1];
                    fre += xv.x * wr - xv.y * wi;
                    fim += xv.x * wi + xv.y * wr;
                }
            }
            sm.p2.Astk[swz(o,       k,      64)] = (f16)fre;
            sm.p2.Astk[swz(o,       32 + k, 64)] = (f16)(-fim);
            sm.p2.Astk[swz(64 + o,  k,      64)] = (f16)fim;
            sm.p2.Astk[swz(64 + o,  32 + k, 64)] = (f16)fre;
        }
    }
    __syncthreads();
    for (int ch = 0; ch < 4; ++ch) {
        f32x4 acc[2][4] = {};
        int rbase = wv * 32;
        for (int ks = 0; ks < 2; ++ks) {
            int k0 = ks * 32 + kq * 8;
            f16x8 bf[4];
#pragma unroll
            for (int nt = 0; nt < 4; ++nt)
                bf[nt] = *(const f16x8*)(CSTtT + (ch * 64 + nt * 16 + ln) * 64 + k0);
#pragma unroll
            for (int mi = 0; mi < 2; ++mi) {
                f16x8 af = *(const f16x8*)(sm.p2.Astk + swz(rbase + mi * 16 + ln, k0, 64));
#pragma unroll
                for (int nt = 0; nt < 4; ++nt)
                    acc[mi][nt] = MFMA16(af, bf[nt], acc[mi][nt]);
            }
        }
        __syncthreads();
#pragma unroll
        for (int mi = 0; mi < 2; ++mi)
#pragma unroll
            for (int nt = 0; nt < 4; ++nt)
#pragma unroll
                for (int r = 0; r < 4; ++r) {
                    int m_e = rbase + mi * 16 + kq * 4 + r;
                    int n_e = nt * 16 + ln;
                    sm.p2.Cbuf[n_e * 136 + m_e] = (f16)acc[mi][nt][r];
                }
        __syncthreads();
        int h_l = t >> 2, seg = t & 3;
        int h_g = ch * 64 + h_l;
        const f16* src = sm.p2.Cbuf + h_l * 136 + seg * 32;
        f16x8 a0 = *(const f16x8*)(src);
        f16x8 a1 = *(const f16x8*)(src + 8);
        f16x8 a2 = *(const f16x8*)(src + 16);
        f16x8 a3 = *(const f16x8*)(src + 24);
        f16* gd = Gmat + ((long)(b * 256 + h_g)) * 4096 + l * 64 + (seg >= 2 ? 2048 : 0) + (seg & 1) * 32;
        *(f16x8*)(gd) = a0;
        *(f16x8*)(gd + 8) = a1;
        *(f16x8*)(gd + 16) = a2;
        *(f16x8*)(gd + 24) = a3;
    }
}

// ---------------------------------------------------------------------------
// K3: per (b,h,half): out[64o x 128w] = gelu( [bw | (1+g)Gt](64x128) @ [xT ; IW](128x128) + bias2 )
// Round-2 probe attribution: 9.4e6 LDS conflict-cycles/rep (~15 us/CU) from
// BT writes at rows==0 mod 4 under swz -> fixed with swz3 (32-bank spread).
// Nontemporal out stores showed 1.34x HBM write amplification -> plain stores.
// ---------------------------------------------------------------------------
__global__ __launch_bounds__(256) void k3_out(
    const float* __restrict__ x, const f16* __restrict__ Gmat,
    const f16* __restrict__ IWT, const float* __restrict__ bypass_w,
    const float* __restrict__ scale, const float* __restrict__ bias2,
    float* __restrict__ out)
{
    __shared__ f16 BT[128 * 128];     // rows: w (local), cols: k (0..63 = i, 64..127 = c)
    __shared__ f16 Amat[64 * 128];    // rows: o, cols: k
    __shared__ float biasSh[64];
    int blk = blockIdx.x, t = threadIdx.x;
    int g = blk >> 4, rr = blk & 15;
    int half = rr >> 3;
    int pair = g * 8 + (rr & 7);
    int b = pair >> 8, h = pair & 255;
    {   // x transpose -> BT[w][i]
        int ipair = t >> 3, q = t & 7;
        const float* xlo = x + ((long)(b * 64 + 2 * ipair) * 256 + h) * 256 + half * 128;
        const float* xhi = xlo + 65536;
        for (int j = 0; j < 4; ++j) {
            int w4 = (q + j * 8) * 4;
            float4 lo = *(const float4*)(xlo + w4);
            float4 hi = *(const float4*)(xhi + w4);
            float lov[4] = {lo.x, lo.y, lo.z, lo.w};
            float hiv[4] = {hi.x, hi.y, hi.z, hi.w};
#pragma unroll
            for (int u = 0; u < 4; ++u) {
                f16x2 pr; pr[0] = (f16)lov[u]; pr[1] = (f16)hiv[u];
                *(f16x2*)(BT + swz3(w4 + u, 2 * ipair, 128)) = pr;
            }
        }
    }
    {   // IWT -> BT[w][64+c]
        int w_l = t >> 1, cs = t & 1;
        const f16* src = IWT + (half * 128 + w_l) * 64 + cs * 32;
        for (int u = 0; u < 8; ++u) {
            f16x4 v = *(const f16x4*)(src + u * 4);
            *(f16x4*)(BT + swz3(w_l, 64 + cs * 32 + u * 4, 128)) = v;
        }
    }
    {   // bypass_w -> Amat[o][i]
        int o = t >> 2, s4 = t & 3;
        const float* bwp = bypass_w + o * 64 + s4 * 16;
        for (int u = 0; u < 4; ++u) {
            float4 v = *(const float4*)(bwp + u * 4);
            f16x4 hv; hv[0] = (f16)v.x; hv[1] = (f16)v.y; hv[2] = (f16)v.z; hv[3] = (f16)v.w;
            *(f16x4*)(Amat + swz(o, s4 * 16 + u * 4, 128)) = hv;
        }
    }
    {   // (1+gamma)*G -> Amat[o][64+c]
        int c = t >> 2, s4 = t & 3;
        const f16* gp = Gmat + ((long)(b * 256 + h) * 64 + c) * 64 + s4 * 16;
        f16x8 g0 = *(const f16x8*)(gp);
        f16x8 g1 = *(const f16x8*)(gp + 8);
        float sc[16];
        for (int qq = 0; qq < 4; ++qq) {
            float4 s = *(const float4*)(scale + b * 64 + s4 * 16 + qq * 4);
            sc[qq * 4 + 0] = s.x; sc[qq * 4 + 1] = s.y; sc[qq * 4 + 2] = s.z; sc[qq * 4 + 3] = s.w;
        }
#pragma unroll
        for (int u = 0; u < 8; ++u) {
            Amat[swz(s4 * 16 + u, 64 + c, 128)] = (f16)((float)g0[u] * sc[u]);
            Amat[swz(s4 * 16 + 8 + u, 64 + c, 128)] = (f16)((float)g1[u] * sc[8 + u]);
        }
    }
    if (t < 64) biasSh[t] = bias2[b * 64 + t];
    __syncthreads();

    int lane = t & 63, wv = t >> 6, kq = lane >> 4, ln = lane & 15;
    f32x4 acc[4][2] = {};
    for (int ks = 0; ks < 4; ++ks) {
        int k0 = ks * 32 + kq * 8;
        f16x8 bf[2];
#pragma unroll
        for (int nt = 0; nt < 2; ++nt)
            bf[nt] = *(const f16x8*)(BT + swz3(wv * 32 + nt * 16 + ln, k0, 128));
#pragma unroll
        for (int mt = 0; mt < 4; ++mt) {
            f16x8 af = *(const f16x8*)(Amat + swz(mt * 16 + ln, k0, 128));
#pragma unroll
            for (int nt = 0; nt < 2; ++nt)
                acc[mt][nt] = MFMA16(af, bf[nt], acc[mt][nt]);
        }
    }
    long obase = ((long)(b * 64) * 256 + h) * 256 + half * 128;
#pragma unroll
    for (int mt = 0; mt < 4; ++mt)
#pragma unroll
        for (int nt = 0; nt < 2; ++nt)
#pragma unroll
            for (int r = 0; r < 4; ++r) {
                int o = mt * 16 + kq * 4 + r;
                int n = wv * 32 + nt * 16 + ln;
                float v = acc[mt][nt][r] + biasSh[o];
                float uu = 0.7978845608028654f * (v + 0.044715f * v * v * v);
                float e = __expf(2.0f * uu);
                float th = 1.0f - 2.0f / (e + 1.0f);
                out[obase + (long)o * 65536 + n] = 0.5f * v * (1.0f + th);
            }
}

// ---------------------------------------------------------------------------
extern "C" void kernel_launch(void* const* d_in, const int* in_sizes, int n_in,
                              void* d_out, int out_size, void* d_ws, size_t ws_size,
                              hipStream_t stream) {
    const float* x        = (const float*)d_in[0];
    const float* t_emb    = (const float*)d_in[1];
    const float* w_real   = (const float*)d_in[2];
    const float* w_imag   = (const float*)d_in[3];
    const float* film_w1  = (const float*)d_in[4];
    const float* film_b1  = (const float*)d_in[5];
    const float* film_w2  = (const float*)d_in[6];
    const float* film_b2  = (const float*)d_in[7];
    const float* bypass_w = (const float*)d_in[8];
    const float* bypass_b = (const float*)d_in[9];
    float* out = (float*)d_out;
    char* ws = (char*)d_ws;

    float* scale = (float*)(ws + 0);          // 4 KB
    float* bias2 = (float*)(ws + 4096);       // 4 KB
    f16* FmatT = (f16*)(ws + 8192);           // 32 KB
    f16* Tab2T = (f16*)(ws + 40960);          // 64 KB
    f16* CSTtT = (f16*)(ws + 106496);         // 32 KB
    f16* IWT   = (f16*)(ws + 139264);         // 32 KB
    f16* wT    = (f16*)(ws + 172032);         // 16 MB
    f16* T1    = (f16*)(ws + 16949248);       // 32 MB
    f16* Gmat  = (f16*)(ws + 50503680);       // 32 MB  (total 84,058,112 B)

    hipLaunchKernelGGL(prep_kernel, dim3(17), dim3(256), 0, stream,
                       t_emb, film_w1, film_b1, film_w2, film_b2, bypass_b,
                       scale, bias2, FmatT, Tab2T, CSTtT, IWT);
    hipLaunchKernelGGL(k1_rowfft, dim3(4352), dim3(256), 0, stream, x, FmatT, T1,
                       w_real, w_imag, wT);
    hipLaunchKernelGGL(k2_spec, dim3(512), dim3(256), 0, stream, T1, Tab2T, wT, CSTtT, Gmat);
    hipLaunchKernelGGL(k3_out, dim3(8192), dim3(256), 0, stream, x, Gmat, IWT,
                       bypass_w, scale, bias2, out);
}